// Round 4
// baseline (140.042 us; speedup 1.0000x reference)
//
#include <hip/hip_runtime.h>
#include <stdint.h>
#include <stddef.h>

#define DIM 1024
#define NEXP 8
#define HID 512
#define NTOK 16384  // 4 * 4096
#define NB_HIST 64  // histogram/scatter blocks (256 tokens each)

typedef __attribute__((ext_vector_type(4))) float f32x4;
typedef __attribute__((ext_vector_type(8))) short short8;
typedef __attribute__((ext_vector_type(4))) unsigned short u16x4;

__device__ __forceinline__ unsigned short f2b(float f) {
  unsigned int u = __float_as_uint(f);
  return (unsigned short)((u + 0x7FFFu + ((u >> 16) & 1u)) >> 16);  // RNE
}

// 16B async global->LDS. lds ptr must be wave-uniform; HW writes base + lane*16.
__device__ __forceinline__ void gload_lds16(const unsigned short* g, unsigned short* l) {
  __builtin_amdgcn_global_load_lds((const __attribute__((address_space(1))) void*)g,
                                   (__attribute__((address_space(3))) void*)l, 16, 0, 0);
}

// One wave per token: 8 router dots (float4), argmax -> eid. FUSED: writes x as bf16.
__global__ __launch_bounds__(256) void k_router(const float* __restrict__ x,
                                                const float* __restrict__ wr,
                                                int* __restrict__ eid,
                                                unsigned short* __restrict__ xb) {
  int wid = threadIdx.x >> 6, lane = threadIdx.x & 63;
  int tok = blockIdx.x * 4 + wid;
  const float* xr = x + (size_t)tok * DIM;
  unsigned short* xbr = xb + (size_t)tok * DIM;
  float s[NEXP];
#pragma unroll
  for (int e = 0; e < NEXP; e++) s[e] = 0.f;
#pragma unroll
  for (int i = 0; i < 4; i++) {
    f32x4 xv = *(const f32x4*)(xr + lane * 4 + 256 * i);
    u16x4 u;
    u.x = f2b(xv.x); u.y = f2b(xv.y); u.z = f2b(xv.z); u.w = f2b(xv.w);
    *(u16x4*)(xbr + lane * 4 + 256 * i) = u;
#pragma unroll
    for (int e = 0; e < NEXP; e++) {
      f32x4 wv = *(const f32x4*)(wr + e * DIM + lane * 4 + 256 * i);
      s[e] += xv.x * wv.x + xv.y * wv.y + xv.z * wv.z + xv.w * wv.w;
    }
  }
#pragma unroll
  for (int e = 0; e < NEXP; e++) {
    float v = s[e];
#pragma unroll
    for (int off = 32; off > 0; off >>= 1) v += __shfl_xor(v, off);
    s[e] = v;
  }
  if (lane == 0) {
    int be = 0;
    float bv = s[0];
#pragma unroll
    for (int e = 1; e < NEXP; e++) {
      if (s[e] > bv) { bv = s[e]; be = e; }
    }
    eid[tok] = be;
  }
}

__global__ __launch_bounds__(256) void k_hist(const int* __restrict__ eid,
                                              int* __restrict__ bc) {
  __shared__ int h[NEXP];
  if (threadIdx.x < NEXP) h[threadIdx.x] = 0;
  __syncthreads();
  int tok = blockIdx.x * (NTOK / NB_HIST) + threadIdx.x;
  atomicAdd(&h[eid[tok]], 1);
  __syncthreads();
  if (threadIdx.x < NEXP) bc[blockIdx.x * NEXP + threadIdx.x] = h[threadIdx.x];
}

__global__ void k_scan(const int* __restrict__ bc, int* __restrict__ offs,
                       int* __restrict__ base) {
  __shared__ int cnt[NEXP];
  __shared__ int so[NEXP + 1];
  int t = threadIdx.x;
  if (t < NEXP) {
    int run = 0;
    for (int b = 0; b < NB_HIST; b++) {
      base[b * NEXP + t] = run;
      run += bc[b * NEXP + t];
    }
    cnt[t] = run;
  }
  __syncthreads();
  if (t == 0) {
    int a = 0;
    for (int e = 0; e < NEXP; e++) { so[e] = a; a += cnt[e]; }
    so[NEXP] = a;
  }
  __syncthreads();
  if (t < NEXP + 1) offs[t] = so[t];
  for (int i = t; i < NB_HIST * NEXP; i += blockDim.x) base[i] += so[i % NEXP];
}

__global__ __launch_bounds__(256) void k_scatter(const int* __restrict__ eid,
                                                 const int* __restrict__ base,
                                                 int* __restrict__ tlist) {
  __shared__ int cur[NEXP];
  if (threadIdx.x < NEXP) cur[threadIdx.x] = base[blockIdx.x * NEXP + threadIdx.x];
  __syncthreads();
  int tok = blockIdx.x * (NTOK / NB_HIST) + threadIdx.x;
  int e = eid[tok];
  int pos = atomicAdd(&cur[e], 1);
  tlist[pos] = tok;
}

__global__ __launch_bounds__(256) void k_cast(const float* __restrict__ a,
                                              const float* __restrict__ b,
                                              unsigned short* __restrict__ oa,
                                              unsigned short* __restrict__ ob) {
  const int n4 = NEXP * HID * DIM / 4;
  int stride = gridDim.x * blockDim.x;
  for (int i = blockIdx.x * blockDim.x + threadIdx.x; i < n4; i += stride) {
    f32x4 va = ((const f32x4*)a)[i];
    f32x4 vb = ((const f32x4*)b)[i];
    u16x4 ua, ub;
    ua.x = f2b(va.x); ua.y = f2b(va.y); ua.z = f2b(va.z); ua.w = f2b(va.w);
    ub.x = f2b(vb.x); ub.y = f2b(vb.y); ub.z = f2b(vb.z); ub.w = f2b(vb.w);
    ((u16x4*)oa)[i] = ua;
    ((u16x4*)ob)[i] = ub;
  }
}

// Grouped GEMM, C[m,n] = sum_k A[m,k]*B[n,k], bf16 operands, K-contiguous.
// Double-buffered LDS, prefetch next K-tile via global_load_lds BEFORE compute,
// raw s_barrier + counted s_waitcnt vmcnt(8) so 8 loads stay in flight across
// the barrier (T3+T4 minimum schedule). XOR-swizzled chunks (rule 21: linear
// LDS dest + inverse-swizzled global source + swizzled ds_read).
// blockIdx.x = flattened (expert, m-block); blockIdx.y = n-block.
template <int KDIM, int NDIM, bool IS_FC>
__global__ __launch_bounds__(256) void k_gemm(
    const unsigned short* __restrict__ xb, const unsigned short* __restrict__ hin,
    const unsigned short* __restrict__ wb, const int* __restrict__ offs,
    const int* __restrict__ tlist, unsigned short* __restrict__ hout,
    float* __restrict__ out) {
  // map flattened block id -> (expert, m-block) by scanning offs (9 ints)
  int e = -1, mb = 0, mac = 0;
#pragma unroll
  for (int i = 0; i < NEXP; i++) {
    int mi = offs[i + 1] - offs[i];
    int nb = (mi + 127) >> 7;
    if (e < 0 && (int)blockIdx.x < mac + nb) { e = i; mb = blockIdx.x - mac; }
    mac += nb;
  }
  if (e < 0) return;
  int off = offs[e];
  int me = offs[e + 1] - off;
  int m0 = mb * 128;
  int n0 = blockIdx.y * 128;

  __shared__ unsigned short As[2][128 * 64];  // 2 x 16 KB
  __shared__ unsigned short Bs[2][128 * 64];  // 2 x 16 KB

  int t = threadIdx.x;
  int lane = t & 63, w = t >> 6;
  int wm = w >> 1, wn = w & 1;  // 2x2 waves, 64x64 each

  // Staging: issue i covers rows i*32 + w*8 + (lane>>3); lane's LDS slot is chunk
  // (lane&7) of its row, which must hold global chunk (lane&7)^(row&7).
  int srow = w * 8 + (lane >> 3);
  int kb = (lane & 7) ^ ((lane >> 3) & 7);

  const unsigned short* asrc[4];
  const unsigned short* bsrc[4];
#pragma unroll
  for (int i = 0; i < 4; i++) {
    int r = i * 32 + srow;
    int gm = m0 + r;
    if (gm > me - 1) gm = me - 1;  // clamp pad rows (masked at epilogue)
    if (IS_FC) {
      int tok = tlist[off + gm];
      asrc[i] = xb + (size_t)tok * KDIM + kb * 8;
    } else {
      asrc[i] = hin + (size_t)(off + gm) * KDIM + kb * 8;
    }
    bsrc[i] = wb + ((size_t)e * NDIM + n0 + r) * (size_t)KDIM + kb * 8;
  }

  f32x4 acc[4][4] = {};
  const int NT = KDIM / 64;

  // prologue: stage tile 0 into buf 0
#pragma unroll
  for (int i = 0; i < 4; i++) {
    gload_lds16(asrc[i], &As[0][i * 2048 + w * 512]);
    gload_lds16(bsrc[i], &Bs[0][i * 2048 + w * 512]);
  }

  for (int kt = 0; kt < NT; kt++) {
    int cur = kt & 1;
    if (kt + 1 < NT) {
      // prefetch next tile into the other buffer (its compute finished last iter)
#pragma unroll
      for (int i = 0; i < 4; i++) {
        gload_lds16(asrc[i] + (kt + 1) * 64, &As[cur ^ 1][i * 2048 + w * 512]);
        gload_lds16(bsrc[i] + (kt + 1) * 64, &Bs[cur ^ 1][i * 2048 + w * 512]);
      }
      asm volatile("s_waitcnt vmcnt(8)" ::: "memory");  // this tile's 8 loads done
    } else {
      asm volatile("s_waitcnt vmcnt(0)" ::: "memory");
    }
    __builtin_amdgcn_s_barrier();  // all waves' current-tile loads visible

    const unsigned short* Ac = As[cur];
    const unsigned short* Bc = Bs[cur];
#pragma unroll
    for (int ks = 0; ks < 2; ks++) {
      short8 af[4], bf[4];
#pragma unroll
      for (int i = 0; i < 4; i++) {
        int ra = wm * 64 + i * 16 + (lane & 15);
        int ca = (ks * 4 + (lane >> 4)) ^ (ra & 7);
        af[i] = *(const short8*)&Ac[ra * 64 + ca * 8];
        int rb = wn * 64 + i * 16 + (lane & 15);
        int cb = (ks * 4 + (lane >> 4)) ^ (rb & 7);
        bf[i] = *(const short8*)&Bc[rb * 64 + cb * 8];
      }
      __builtin_amdgcn_s_setprio(1);
#pragma unroll
      for (int mi = 0; mi < 4; mi++)
#pragma unroll
        for (int ni = 0; ni < 4; ni++)
          acc[mi][ni] =
              __builtin_amdgcn_mfma_f32_16x16x32_bf16(af[mi], bf[ni], acc[mi][ni], 0, 0, 0);
      __builtin_amdgcn_s_setprio(0);
    }
    __builtin_amdgcn_s_barrier();  // compute done before next prefetch overwrites
  }

  // C/D layout: col = lane&15, row = (lane>>4)*4 + reg
  int rb = (lane >> 4) * 4, cb = lane & 15;
#pragma unroll
  for (int mi = 0; mi < 4; mi++) {
#pragma unroll
    for (int j = 0; j < 4; j++) {
      int ml = wm * 64 + mi * 16 + rb + j;
      if (m0 + ml < me) {
        if (IS_FC) {
#pragma unroll
          for (int ni = 0; ni < 4; ni++) {
            int col = n0 + wn * 64 + ni * 16 + cb;
            float v = acc[mi][ni][j];
            v = (v >= 0.f) ? v * v : 0.25f * v * v;  // leaky(0.5) then square
            hout[(size_t)(off + m0 + ml) * HID + col] = f2b(v);
          }
        } else {
          int tok = tlist[off + m0 + ml];
#pragma unroll
          for (int ni = 0; ni < 4; ni++) {
            int col = n0 + wn * 64 + ni * 16 + cb;
            out[(size_t)tok * DIM + col] = acc[mi][ni][j];
          }
        }
      }
    }
  }
}

extern "C" void kernel_launch(void* const* d_in, const int* in_sizes, int n_in,
                              void* d_out, int out_size, void* d_ws, size_t ws_size,
                              hipStream_t stream) {
  const float* x = (const float*)d_in[0];
  const float* wr = (const float*)d_in[1];
  const float* wfc = (const float*)d_in[2];
  const float* wpj = (const float*)d_in[3];
  float* out = (float*)d_out;

  uintptr_t p = (uintptr_t)d_ws;
  int* offs = (int*)p;  p += 256;
  int* bc = (int*)p;    p += sizeof(int) * NB_HIST * NEXP;
  int* base = (int*)p;  p += sizeof(int) * NB_HIST * NEXP;
  int* eid = (int*)p;   p += sizeof(int) * NTOK;
  int* tlist = (int*)p; p += sizeof(int) * NTOK;
  unsigned short* wfc_b = (unsigned short*)p; p += (size_t)NEXP * HID * DIM * 2;
  unsigned short* wpj_b = (unsigned short*)p; p += (size_t)NEXP * DIM * HID * 2;
  unsigned short* hbuf = (unsigned short*)p;  p += (size_t)NTOK * HID * 2;
  unsigned short* xb = (unsigned short*)p;    p += (size_t)NTOK * DIM * 2;

  k_router<<<NTOK / 4, 256, 0, stream>>>(x, wr, eid, xb);
  k_cast<<<1024, 256, 0, stream>>>(wfc, wpj, wfc_b, wpj_b);
  k_hist<<<NB_HIST, 256, 0, stream>>>(eid, bc);
  k_scan<<<1, 256, 0, stream>>>(bc, offs, base);
  k_scatter<<<NB_HIST, 256, 0, stream>>>(eid, base, tlist);
  // grid.x = max total m-blocks across experts: sum ceil(me/128) <= 128 + 7 = 135
  k_gemm<1024, 512, true><<<dim3(135, 4), 256, 0, stream>>>(
      xb, nullptr, wfc_b, offs, tlist, hbuf, nullptr);
  k_gemm<512, 1024, false><<<dim3(135, 8), 256, 0, stream>>>(
      nullptr, hbuf, wpj_b, offs, tlist, nullptr, out);
}

// Round 5
// 119.571 us; speedup vs baseline: 1.1712x; 1.1712x over previous
//
#include <hip/hip_runtime.h>
#include <stdint.h>
#include <stddef.h>

#define DIM 1024
#define NEXP 8
#define HID 512
#define NTOK 16384  // 4 * 4096
#define NB_HIST 64  // histogram/scatter blocks (256 tokens each)

typedef __attribute__((ext_vector_type(4))) float f32x4;
typedef __attribute__((ext_vector_type(8))) short short8;
typedef __attribute__((ext_vector_type(4))) unsigned short u16x4;

__device__ __forceinline__ unsigned short f2b(float f) {
  unsigned int u = __float_as_uint(f);
  return (unsigned short)((u + 0x7FFFu + ((u >> 16) & 1u)) >> 16);  // RNE
}

// 16B async global->LDS. lds ptr must be wave-uniform; HW writes base + lane*16.
__device__ __forceinline__ void gload_lds16(const unsigned short* g, unsigned short* l) {
  __builtin_amdgcn_global_load_lds((const __attribute__((address_space(1))) void*)g,
                                   (__attribute__((address_space(3))) void*)l, 16, 0, 0);
}

// One wave per token: 8 router dots (float4), argmax -> eid. FUSED: writes x as bf16.
__global__ __launch_bounds__(256) void k_router(const float* __restrict__ x,
                                                const float* __restrict__ wr,
                                                int* __restrict__ eid,
                                                unsigned short* __restrict__ xb) {
  int wid = threadIdx.x >> 6, lane = threadIdx.x & 63;
  int tok = blockIdx.x * 4 + wid;
  const float* xr = x + (size_t)tok * DIM;
  unsigned short* xbr = xb + (size_t)tok * DIM;
  float s[NEXP];
#pragma unroll
  for (int e = 0; e < NEXP; e++) s[e] = 0.f;
#pragma unroll
  for (int i = 0; i < 4; i++) {
    f32x4 xv = *(const f32x4*)(xr + lane * 4 + 256 * i);
    u16x4 u;
    u.x = f2b(xv.x); u.y = f2b(xv.y); u.z = f2b(xv.z); u.w = f2b(xv.w);
    *(u16x4*)(xbr + lane * 4 + 256 * i) = u;
#pragma unroll
    for (int e = 0; e < NEXP; e++) {
      f32x4 wv = *(const f32x4*)(wr + e * DIM + lane * 4 + 256 * i);
      s[e] += xv.x * wv.x + xv.y * wv.y + xv.z * wv.z + xv.w * wv.w;
    }
  }
#pragma unroll
  for (int e = 0; e < NEXP; e++) {
    float v = s[e];
#pragma unroll
    for (int off = 32; off > 0; off >>= 1) v += __shfl_xor(v, off);
    s[e] = v;
  }
  if (lane == 0) {
    int be = 0;
    float bv = s[0];
#pragma unroll
    for (int e = 1; e < NEXP; e++) {
      if (s[e] > bv) { bv = s[e]; be = e; }
    }
    eid[tok] = be;
  }
}

__global__ __launch_bounds__(256) void k_hist(const int* __restrict__ eid,
                                              int* __restrict__ bc) {
  __shared__ int h[NEXP];
  if (threadIdx.x < NEXP) h[threadIdx.x] = 0;
  __syncthreads();
  int tok = blockIdx.x * (NTOK / NB_HIST) + threadIdx.x;
  atomicAdd(&h[eid[tok]], 1);
  __syncthreads();
  if (threadIdx.x < NEXP) bc[blockIdx.x * NEXP + threadIdx.x] = h[threadIdx.x];
}

__global__ void k_scan(const int* __restrict__ bc, int* __restrict__ offs,
                       int* __restrict__ base) {
  __shared__ int cnt[NEXP];
  __shared__ int so[NEXP + 1];
  int t = threadIdx.x;
  if (t < NEXP) {
    int run = 0;
    for (int b = 0; b < NB_HIST; b++) {
      base[b * NEXP + t] = run;
      run += bc[b * NEXP + t];
    }
    cnt[t] = run;
  }
  __syncthreads();
  if (t == 0) {
    int a = 0;
    for (int e = 0; e < NEXP; e++) { so[e] = a; a += cnt[e]; }
    so[NEXP] = a;
  }
  __syncthreads();
  if (t < NEXP + 1) offs[t] = so[t];
  for (int i = t; i < NB_HIST * NEXP; i += blockDim.x) base[i] += so[i % NEXP];
}

__global__ __launch_bounds__(256) void k_scatter(const int* __restrict__ eid,
                                                 const int* __restrict__ base,
                                                 int* __restrict__ tlist) {
  __shared__ int cur[NEXP];
  if (threadIdx.x < NEXP) cur[threadIdx.x] = base[blockIdx.x * NEXP + threadIdx.x];
  __syncthreads();
  int tok = blockIdx.x * (NTOK / NB_HIST) + threadIdx.x;
  int e = eid[tok];
  int pos = atomicAdd(&cur[e], 1);
  tlist[pos] = tok;
}

__global__ __launch_bounds__(256) void k_cast(const float* __restrict__ a,
                                              const float* __restrict__ b,
                                              unsigned short* __restrict__ oa,
                                              unsigned short* __restrict__ ob) {
  const int n4 = NEXP * HID * DIM / 4;
  int stride = gridDim.x * blockDim.x;
  for (int i = blockIdx.x * blockDim.x + threadIdx.x; i < n4; i += stride) {
    f32x4 va = ((const f32x4*)a)[i];
    f32x4 vb = ((const f32x4*)b)[i];
    u16x4 ua, ub;
    ua.x = f2b(va.x); ua.y = f2b(va.y); ua.z = f2b(va.z); ua.w = f2b(va.w);
    ub.x = f2b(vb.x); ub.y = f2b(vb.y); ub.z = f2b(vb.z); ub.w = f2b(vb.w);
    ((u16x4*)oa)[i] = ua;
    ((u16x4*)ob)[i] = ub;
  }
}

// Grouped GEMM, C[m,n] = sum_k A[m,k]*B[n,k], bf16 operands, K-contiguous.
// Double-buffered LDS, next K-tile prefetched via global_load_lds before compute,
// raw s_barrier + counted s_waitcnt vmcnt(8) (T3+T4 minimum schedule), XOR-swizzled
// chunks (rule 21). 1-D grid with T1 chunked XCD swizzle; logical tile order is
// (expert, m-block, n-block) with n-block FASTEST so the NB consecutive tiles on
// one XCD share an A panel, and each expert's B slab stays in that XCD's L2
// (round-4 lesson: n-outer ordering refetched A 8x -> 99 MB, 3.2 TB/s wasted).
template <int KDIM, int NDIM, int NB, bool IS_FC>
__global__ __launch_bounds__(256) void k_gemm(
    const unsigned short* __restrict__ xb, const unsigned short* __restrict__ hin,
    const unsigned short* __restrict__ wb, const int* __restrict__ offs,
    const int* __restrict__ tlist, unsigned short* __restrict__ hout,
    float* __restrict__ out) {
  // XCD chunk swizzle (gridDim.x % 8 == 0): XCD c owns logical ids [c*G/8,(c+1)*G/8)
  int l = ((int)blockIdx.x & 7) * ((int)gridDim.x >> 3) + ((int)blockIdx.x >> 3);
  // logical id -> (expert, m-block, n-block), n fastest
  int e = -1, mb = 0, nb = 0, acc2 = 0;
#pragma unroll
  for (int i = 0; i < NEXP; i++) {
    int mi = offs[i + 1] - offs[i];
    int tb = ((mi + 127) >> 7) * NB;
    if (e < 0 && l < acc2 + tb) {
      int r = l - acc2;
      e = i; mb = r / NB; nb = r % NB;
    }
    acc2 += tb;
  }
  if (e < 0) return;
  int off = offs[e];
  int me = offs[e + 1] - off;
  int m0 = mb * 128;
  int n0 = nb * 128;

  __shared__ unsigned short As[2][128 * 64];  // 2 x 16 KB
  __shared__ unsigned short Bs[2][128 * 64];  // 2 x 16 KB

  int t = threadIdx.x;
  int lane = t & 63, w = t >> 6;
  int wm = w >> 1, wn = w & 1;  // 2x2 waves, 64x64 each

  // Staging: issue i covers rows i*32 + w*8 + (lane>>3); lane's LDS slot is chunk
  // (lane&7) of its row, which must hold global chunk (lane&7)^(row&7).
  int srow = w * 8 + (lane >> 3);
  int kb = (lane & 7) ^ ((lane >> 3) & 7);

  const unsigned short* asrc[4];
  const unsigned short* bsrc[4];
#pragma unroll
  for (int i = 0; i < 4; i++) {
    int r = i * 32 + srow;
    int gm = m0 + r;
    if (gm > me - 1) gm = me - 1;  // clamp pad rows (masked at epilogue)
    if (IS_FC) {
      int tok = tlist[off + gm];
      asrc[i] = xb + (size_t)tok * KDIM + kb * 8;
    } else {
      asrc[i] = hin + (size_t)(off + gm) * KDIM + kb * 8;
    }
    bsrc[i] = wb + ((size_t)e * NDIM + n0 + r) * (size_t)KDIM + kb * 8;
  }

  f32x4 acc[4][4] = {};
  const int NT = KDIM / 64;

  // prologue: stage tile 0 into buf 0
#pragma unroll
  for (int i = 0; i < 4; i++) {
    gload_lds16(asrc[i], &As[0][i * 2048 + w * 512]);
    gload_lds16(bsrc[i], &Bs[0][i * 2048 + w * 512]);
  }

  for (int kt = 0; kt < NT; kt++) {
    int cur = kt & 1;
    if (kt + 1 < NT) {
#pragma unroll
      for (int i = 0; i < 4; i++) {
        gload_lds16(asrc[i] + (kt + 1) * 64, &As[cur ^ 1][i * 2048 + w * 512]);
        gload_lds16(bsrc[i] + (kt + 1) * 64, &Bs[cur ^ 1][i * 2048 + w * 512]);
      }
      asm volatile("s_waitcnt vmcnt(8)" ::: "memory");  // this tile's 8 loads done
    } else {
      asm volatile("s_waitcnt vmcnt(0)" ::: "memory");
    }
    __builtin_amdgcn_s_barrier();  // all waves' current-tile loads visible

    const unsigned short* Ac = As[cur];
    const unsigned short* Bc = Bs[cur];
#pragma unroll
    for (int ks = 0; ks < 2; ks++) {
      short8 af[4], bf[4];
#pragma unroll
      for (int i = 0; i < 4; i++) {
        int ra = wm * 64 + i * 16 + (lane & 15);
        int ca = (ks * 4 + (lane >> 4)) ^ (ra & 7);
        af[i] = *(const short8*)&Ac[ra * 64 + ca * 8];
        int rb = wn * 64 + i * 16 + (lane & 15);
        int cb = (ks * 4 + (lane >> 4)) ^ (rb & 7);
        bf[i] = *(const short8*)&Bc[rb * 64 + cb * 8];
      }
      __builtin_amdgcn_s_setprio(1);
#pragma unroll
      for (int mi = 0; mi < 4; mi++)
#pragma unroll
        for (int ni = 0; ni < 4; ni++)
          acc[mi][ni] =
              __builtin_amdgcn_mfma_f32_16x16x32_bf16(af[mi], bf[ni], acc[mi][ni], 0, 0, 0);
      __builtin_amdgcn_s_setprio(0);
    }
    __builtin_amdgcn_s_barrier();  // compute done before next prefetch overwrites
  }

  // C/D layout: col = lane&15, row = (lane>>4)*4 + reg
  int rb = (lane >> 4) * 4, cb = lane & 15;
#pragma unroll
  for (int mi = 0; mi < 4; mi++) {
#pragma unroll
    for (int j = 0; j < 4; j++) {
      int ml = wm * 64 + mi * 16 + rb + j;
      if (m0 + ml < me) {
        if (IS_FC) {
#pragma unroll
          for (int ni = 0; ni < 4; ni++) {
            int col = n0 + wn * 64 + ni * 16 + cb;
            float v = acc[mi][ni][j];
            v = (v >= 0.f) ? v * v : 0.25f * v * v;  // leaky(0.5) then square
            hout[(size_t)(off + m0 + ml) * HID + col] = f2b(v);
          }
        } else {
          int tok = tlist[off + m0 + ml];
#pragma unroll
          for (int ni = 0; ni < 4; ni++) {
            int col = n0 + wn * 64 + ni * 16 + cb;
            out[(size_t)tok * DIM + col] = acc[mi][ni][j];
          }
        }
      }
    }
  }
}

extern "C" void kernel_launch(void* const* d_in, const int* in_sizes, int n_in,
                              void* d_out, int out_size, void* d_ws, size_t ws_size,
                              hipStream_t stream) {
  const float* x = (const float*)d_in[0];
  const float* wr = (const float*)d_in[1];
  const float* wfc = (const float*)d_in[2];
  const float* wpj = (const float*)d_in[3];
  float* out = (float*)d_out;

  uintptr_t p = (uintptr_t)d_ws;
  int* offs = (int*)p;  p += 256;
  int* bc = (int*)p;    p += sizeof(int) * NB_HIST * NEXP;
  int* base = (int*)p;  p += sizeof(int) * NB_HIST * NEXP;
  int* eid = (int*)p;   p += sizeof(int) * NTOK;
  int* tlist = (int*)p; p += sizeof(int) * NTOK;
  unsigned short* wfc_b = (unsigned short*)p; p += (size_t)NEXP * HID * DIM * 2;
  unsigned short* wpj_b = (unsigned short*)p; p += (size_t)NEXP * DIM * HID * 2;
  unsigned short* hbuf = (unsigned short*)p;  p += (size_t)NTOK * HID * 2;
  unsigned short* xb = (unsigned short*)p;    p += (size_t)NTOK * DIM * 2;

  k_router<<<NTOK / 4, 256, 0, stream>>>(x, wr, eid, xb);
  k_cast<<<1024, 256, 0, stream>>>(wfc, wpj, wfc_b, wpj_b);
  k_hist<<<NB_HIST, 256, 0, stream>>>(eid, bc);
  k_scan<<<1, 256, 0, stream>>>(bc, offs, base);
  k_scatter<<<NB_HIST, 256, 0, stream>>>(eid, base, tlist);
  // fc: max tiles = 135 m-blocks * 4 n-blocks = 540 -> grid 544 (divisible by 8)
  k_gemm<1024, 512, 4, true><<<dim3(544), 256, 0, stream>>>(
      xb, nullptr, wfc_b, offs, tlist, hbuf, nullptr);
  // proj: max tiles = 135 * 8 = 1080 (divisible by 8)
  k_gemm<512, 1024, 8, false><<<dim3(1080), 256, 0, stream>>>(
      nullptr, hbuf, wpj_b, offs, tlist, nullptr, out);
}

// Round 6
// 112.629 us; speedup vs baseline: 1.2434x; 1.0616x over previous
//
#include <hip/hip_runtime.h>
#include <stdint.h>
#include <stddef.h>

#define DIM 1024
#define NEXP 8
#define HID 512
#define NTOK 16384  // 4 * 4096
#define NB_HIST 64  // histogram/scatter blocks (256 tokens each)

typedef __attribute__((ext_vector_type(4))) float f32x4;
typedef __attribute__((ext_vector_type(8))) short short8;
typedef __attribute__((ext_vector_type(4))) unsigned short u16x4;

__device__ __forceinline__ unsigned short f2b(float f) {
  unsigned int u = __float_as_uint(f);
  return (unsigned short)((u + 0x7FFFu + ((u >> 16) & 1u)) >> 16);  // RNE
}

// 16B async global->LDS. lds ptr must be wave-uniform; HW writes base + lane*16.
__device__ __forceinline__ void gload_lds16(const unsigned short* g, unsigned short* l) {
  __builtin_amdgcn_global_load_lds((const __attribute__((address_space(1))) void*)g,
                                   (__attribute__((address_space(3))) void*)l, 16, 0, 0);
}

// One wave per token: 8 router dots (float4), argmax -> eid. FUSED: writes x as bf16.
__global__ __launch_bounds__(256) void k_router(const float* __restrict__ x,
                                                const float* __restrict__ wr,
                                                int* __restrict__ eid,
                                                unsigned short* __restrict__ xb) {
  int wid = threadIdx.x >> 6, lane = threadIdx.x & 63;
  int tok = blockIdx.x * 4 + wid;
  const float* xr = x + (size_t)tok * DIM;
  unsigned short* xbr = xb + (size_t)tok * DIM;
  float s[NEXP];
#pragma unroll
  for (int e = 0; e < NEXP; e++) s[e] = 0.f;
#pragma unroll
  for (int i = 0; i < 4; i++) {
    f32x4 xv = *(const f32x4*)(xr + lane * 4 + 256 * i);
    u16x4 u;
    u.x = f2b(xv.x); u.y = f2b(xv.y); u.z = f2b(xv.z); u.w = f2b(xv.w);
    *(u16x4*)(xbr + lane * 4 + 256 * i) = u;
#pragma unroll
    for (int e = 0; e < NEXP; e++) {
      f32x4 wv = *(const f32x4*)(wr + e * DIM + lane * 4 + 256 * i);
      s[e] += xv.x * wv.x + xv.y * wv.y + xv.z * wv.z + xv.w * wv.w;
    }
  }
#pragma unroll
  for (int e = 0; e < NEXP; e++) {
    float v = s[e];
#pragma unroll
    for (int off = 32; off > 0; off >>= 1) v += __shfl_xor(v, off);
    s[e] = v;
  }
  if (lane == 0) {
    int be = 0;
    float bv = s[0];
#pragma unroll
    for (int e = 1; e < NEXP; e++) {
      if (s[e] > bv) { bv = s[e]; be = e; }
    }
    eid[tok] = be;
  }
}

__global__ __launch_bounds__(256) void k_hist(const int* __restrict__ eid,
                                              int* __restrict__ bc) {
  __shared__ int h[NEXP];
  if (threadIdx.x < NEXP) h[threadIdx.x] = 0;
  __syncthreads();
  int tok = blockIdx.x * (NTOK / NB_HIST) + threadIdx.x;
  atomicAdd(&h[eid[tok]], 1);
  __syncthreads();
  if (threadIdx.x < NEXP) bc[blockIdx.x * NEXP + threadIdx.x] = h[threadIdx.x];
}

__global__ void k_scan(const int* __restrict__ bc, int* __restrict__ offs,
                       int* __restrict__ base) {
  __shared__ int cnt[NEXP];
  __shared__ int so[NEXP + 1];
  int t = threadIdx.x;
  if (t < NEXP) {
    int run = 0;
    for (int b = 0; b < NB_HIST; b++) {
      base[b * NEXP + t] = run;
      run += bc[b * NEXP + t];
    }
    cnt[t] = run;
  }
  __syncthreads();
  if (t == 0) {
    int a = 0;
    for (int e = 0; e < NEXP; e++) { so[e] = a; a += cnt[e]; }
    so[NEXP] = a;
  }
  __syncthreads();
  if (t < NEXP + 1) offs[t] = so[t];
  for (int i = t; i < NB_HIST * NEXP; i += blockDim.x) base[i] += so[i % NEXP];
}

__global__ __launch_bounds__(256) void k_scatter(const int* __restrict__ eid,
                                                 const int* __restrict__ base,
                                                 int* __restrict__ tlist) {
  __shared__ int cur[NEXP];
  if (threadIdx.x < NEXP) cur[threadIdx.x] = base[blockIdx.x * NEXP + threadIdx.x];
  __syncthreads();
  int tok = blockIdx.x * (NTOK / NB_HIST) + threadIdx.x;
  int e = eid[tok];
  int pos = atomicAdd(&cur[e], 1);
  tlist[pos] = tok;
}

__global__ __launch_bounds__(256) void k_cast(const float* __restrict__ a,
                                              const float* __restrict__ b,
                                              unsigned short* __restrict__ oa,
                                              unsigned short* __restrict__ ob) {
  const int n4 = NEXP * HID * DIM / 4;
  int stride = gridDim.x * blockDim.x;
  for (int i = blockIdx.x * blockDim.x + threadIdx.x; i < n4; i += stride) {
    f32x4 va = ((const f32x4*)a)[i];
    f32x4 vb = ((const f32x4*)b)[i];
    u16x4 ua, ub;
    ua.x = f2b(va.x); ua.y = f2b(va.y); ua.z = f2b(va.z); ua.w = f2b(va.w);
    ub.x = f2b(vb.x); ub.y = f2b(vb.y); ub.z = f2b(vb.z); ub.w = f2b(vb.w);
    ((u16x4*)oa)[i] = ua;
    ((u16x4*)ob)[i] = ub;
  }
}

// Grouped GEMM, C[m,n] = sum_k A[m,k]*B[n,k], bf16, K-contiguous.
// Round-6 schedule: BK=32, RING-3 LDS (48 KB -> 3 blocks/CU), DEPTH-2 prefetch
// (tile kt issued 2 iters before use; ~2 compute-phases of latency budget covers
// the shared-panel HBM miss that round-5's depth-1 couldn't), ONE barrier/step,
// counted vmcnt(4) (0 only on the last step). XOR swizzle per 64B row:
// chunk ^= row&3 (worst 2-way = free). XCD-chunked n-fastest tile order kept.
template <int KDIM, int NDIM, int NB, bool IS_FC>
__global__ __launch_bounds__(256) void k_gemm(
    const unsigned short* __restrict__ xb, const unsigned short* __restrict__ hin,
    const unsigned short* __restrict__ wb, const int* __restrict__ offs,
    const int* __restrict__ tlist, unsigned short* __restrict__ hout,
    float* __restrict__ out) {
  // XCD chunk swizzle (gridDim.x % 8 == 0)
  int l = ((int)blockIdx.x & 7) * ((int)gridDim.x >> 3) + ((int)blockIdx.x >> 3);
  // logical id -> (expert, m-block, n-block), n fastest
  int e = -1, mb = 0, nb = 0, acc2 = 0;
#pragma unroll
  for (int i = 0; i < NEXP; i++) {
    int mi = offs[i + 1] - offs[i];
    int tb = ((mi + 127) >> 7) * NB;
    if (e < 0 && l < acc2 + tb) {
      int r = l - acc2;
      e = i; mb = r / NB; nb = r % NB;
    }
    acc2 += tb;
  }
  if (e < 0) return;
  int off = offs[e];
  int me = offs[e + 1] - off;
  int m0 = mb * 128;
  int n0 = nb * 128;

  // ring-3: [ring][A=0/B=1][128 rows x 32 cols]
  __shared__ unsigned short lds[3][2][128 * 32];  // 48 KB

  int t = threadIdx.x;
  int lane = t & 63, w = t >> 6;
  int wm = w >> 1, wn = w & 1;  // 2x2 waves, 64x64 each

  // Staging (BK=32): issue i in {0,1} covers rows i*64 + w*16 + (lane>>2);
  // lane's LDS chunk slot is (lane&3); it must hold global chunk (lane&3)^(row&3),
  // row&3 == (lane>>2)&3.
  int kb = (lane & 3) ^ ((lane >> 2) & 3);

  const unsigned short* asrc[2];
  const unsigned short* bsrc[2];
#pragma unroll
  for (int i = 0; i < 2; i++) {
    int r = i * 64 + w * 16 + (lane >> 2);
    int gm = m0 + r;
    if (gm > me - 1) gm = me - 1;  // clamp pad rows (masked at epilogue)
    if (IS_FC) {
      int tok = tlist[off + gm];
      asrc[i] = xb + (size_t)tok * KDIM + kb * 8;
    } else {
      asrc[i] = hin + (size_t)(off + gm) * KDIM + kb * 8;
    }
    bsrc[i] = wb + ((size_t)e * NDIM + n0 + r) * (size_t)KDIM + kb * 8;
  }

  f32x4 acc[4][4] = {};
  const int NT = KDIM / 32;

  unsigned short* b0a = &lds[0][0][0]; unsigned short* b0b = &lds[0][1][0];
  unsigned short* b1a = &lds[1][0][0]; unsigned short* b1b = &lds[1][1][0];
  unsigned short* b2a = &lds[2][0][0]; unsigned short* b2b = &lds[2][1][0];

#define STAGE(kt_, da_, db_)                                   \
  do {                                                         \
    gload_lds16(asrc[0] + (kt_) * 32, (da_) + (w * 16) * 32);  \
    gload_lds16(asrc[1] + (kt_) * 32, (da_) + (64 + w * 16) * 32); \
    gload_lds16(bsrc[0] + (kt_) * 32, (db_) + (w * 16) * 32);  \
    gload_lds16(bsrc[1] + (kt_) * 32, (db_) + (64 + w * 16) * 32); \
  } while (0)

  // prologue: tiles 0 and 1 in flight (depth 2)
  STAGE(0, b0a, b0b);
  STAGE(1, b1a, b1b);

  for (int kt = 0; kt < NT; kt++) {
    // wait for tile kt's 4 loads (issued 2 iterations ago); keep kt+1's 4 in flight
    if (kt < NT - 1) {
      asm volatile("s_waitcnt vmcnt(4)" ::: "memory");
    } else {
      asm volatile("s_waitcnt vmcnt(0)" ::: "memory");
    }
    __builtin_amdgcn_s_barrier();  // kt loads visible; all waves done with b2's old tile

    if (kt + 2 < NT) STAGE(kt + 2, b2a, b2b);

    short8 af[4], bf[4];
#pragma unroll
    for (int i = 0; i < 4; i++) {
      int ra = wm * 64 + i * 16 + (lane & 15);
      int ca = (lane >> 4) ^ (ra & 3);
      af[i] = *(const short8*)&b0a[ra * 32 + ca * 8];
      int rb = wn * 64 + i * 16 + (lane & 15);
      int cb = (lane >> 4) ^ (rb & 3);
      bf[i] = *(const short8*)&b0b[rb * 32 + cb * 8];
    }
    __builtin_amdgcn_s_setprio(1);
#pragma unroll
    for (int mi = 0; mi < 4; mi++)
#pragma unroll
      for (int ni = 0; ni < 4; ni++)
        acc[mi][ni] =
            __builtin_amdgcn_mfma_f32_16x16x32_bf16(af[mi], bf[ni], acc[mi][ni], 0, 0, 0);
    __builtin_amdgcn_s_setprio(0);

    // rotate ring: (b0,b1,b2) <- (b1,b2,b0)
    unsigned short* ta = b0a; b0a = b1a; b1a = b2a; b2a = ta;
    unsigned short* tb = b0b; b0b = b1b; b1b = b2b; b2b = tb;
  }
#undef STAGE

  // C/D layout: col = lane&15, row = (lane>>4)*4 + reg
  int rb = (lane >> 4) * 4, cb = lane & 15;
#pragma unroll
  for (int mi = 0; mi < 4; mi++) {
#pragma unroll
    for (int j = 0; j < 4; j++) {
      int ml = wm * 64 + mi * 16 + rb + j;
      if (m0 + ml < me) {
        if (IS_FC) {
#pragma unroll
          for (int ni = 0; ni < 4; ni++) {
            int col = n0 + wn * 64 + ni * 16 + cb;
            float v = acc[mi][ni][j];
            v = (v >= 0.f) ? v * v : 0.25f * v * v;  // leaky(0.5) then square
            hout[(size_t)(off + m0 + ml) * HID + col] = f2b(v);
          }
        } else {
          int tok = tlist[off + m0 + ml];
#pragma unroll
          for (int ni = 0; ni < 4; ni++) {
            int col = n0 + wn * 64 + ni * 16 + cb;
            out[(size_t)tok * DIM + col] = acc[mi][ni][j];
          }
        }
      }
    }
  }
}

extern "C" void kernel_launch(void* const* d_in, const int* in_sizes, int n_in,
                              void* d_out, int out_size, void* d_ws, size_t ws_size,
                              hipStream_t stream) {
  const float* x = (const float*)d_in[0];
  const float* wr = (const float*)d_in[1];
  const float* wfc = (const float*)d_in[2];
  const float* wpj = (const float*)d_in[3];
  float* out = (float*)d_out;

  uintptr_t p = (uintptr_t)d_ws;
  int* offs = (int*)p;  p += 256;
  int* bc = (int*)p;    p += sizeof(int) * NB_HIST * NEXP;
  int* base = (int*)p;  p += sizeof(int) * NB_HIST * NEXP;
  int* eid = (int*)p;   p += sizeof(int) * NTOK;
  int* tlist = (int*)p; p += sizeof(int) * NTOK;
  unsigned short* wfc_b = (unsigned short*)p; p += (size_t)NEXP * HID * DIM * 2;
  unsigned short* wpj_b = (unsigned short*)p; p += (size_t)NEXP * DIM * HID * 2;
  unsigned short* hbuf = (unsigned short*)p;  p += (size_t)NTOK * HID * 2;
  unsigned short* xb = (unsigned short*)p;    p += (size_t)NTOK * DIM * 2;

  k_router<<<NTOK / 4, 256, 0, stream>>>(x, wr, eid, xb);
  k_cast<<<1024, 256, 0, stream>>>(wfc, wpj, wfc_b, wpj_b);
  k_hist<<<NB_HIST, 256, 0, stream>>>(eid, bc);
  k_scan<<<1, 256, 0, stream>>>(bc, offs, base);
  k_scatter<<<NB_HIST, 256, 0, stream>>>(eid, base, tlist);
  // fc: max tiles = 135 m-blocks * 4 n-blocks = 540 -> grid 544 (divisible by 8)
  k_gemm<1024, 512, 4, true><<<dim3(544), 256, 0, stream>>>(
      xb, nullptr, wfc_b, offs, tlist, hbuf, nullptr);
  // proj: max tiles = 135 * 8 = 1080 (divisible by 8)
  k_gemm<512, 1024, 8, false><<<dim3(1080), 256, 0, stream>>>(
      nullptr, hbuf, wpj_b, offs, tlist, nullptr, out);
}

// Round 7
// 111.308 us; speedup vs baseline: 1.2581x; 1.0119x over previous
//
#include <hip/hip_runtime.h>
#include <stdint.h>
#include <stddef.h>

#define DIM 1024
#define NEXP 8
#define HID 512
#define NTOK 16384  // 4 * 4096
#define NB_HIST 64  // histogram/scatter blocks (256 tokens each)
#define NB_ROUTER 1024  // router blocks (16 tokens each)
#define NB_CAST 512     // cast blocks appended to the router grid

typedef __attribute__((ext_vector_type(4))) float f32x4;
typedef __attribute__((ext_vector_type(8))) short short8;
typedef __attribute__((ext_vector_type(4))) unsigned short u16x4;

__device__ __forceinline__ unsigned short f2b(float f) {
  unsigned int u = __float_as_uint(f);
  return (unsigned short)((u + 0x7FFFu + ((u >> 16) & 1u)) >> 16);  // RNE
}

// 16B async global->LDS. lds ptr must be wave-uniform; HW writes base + lane*16.
__device__ __forceinline__ void gload_lds16(const unsigned short* g, unsigned short* l) {
  __builtin_amdgcn_global_load_lds((const __attribute__((address_space(1))) void*)g,
                                   (__attribute__((address_space(3))) void*)l, 16, 0, 0);
}

// Fused router + weight-cast (round-7: two independent memory-bound kernels were
// serialized; fusing interleaves their traffic across CUs).
// Blocks [0,NB_ROUTER): router, 4 waves x 4 tokens/wave (4 independent FMA chains
// per wr load -> ILP; round-6 router was latency-bound at 1.6 TB/s).
// Blocks [NB_ROUTER, NB_ROUTER+NB_CAST): grid-stride fp32->bf16 cast of both
// weight tensors.
__global__ __launch_bounds__(256) void k_router_cast(
    const float* __restrict__ x, const float* __restrict__ wr,
    int* __restrict__ eid, unsigned short* __restrict__ xb,
    const float* __restrict__ wfc, const float* __restrict__ wpj,
    unsigned short* __restrict__ oa, unsigned short* __restrict__ ob) {
  int bid = blockIdx.x;
  if (bid < NB_ROUTER) {
    int w = threadIdx.x >> 6, lane = threadIdx.x & 63;
    int t0 = bid * 16 + w * 4;  // 4 tokens per wave
    const float* xr = x + (size_t)t0 * DIM;
    unsigned short* xbr = xb + (size_t)t0 * DIM;
    float s[4][NEXP];
#pragma unroll
    for (int j = 0; j < 4; j++)
#pragma unroll
      for (int e = 0; e < NEXP; e++) s[j][e] = 0.f;
#pragma unroll
    for (int i = 0; i < 4; i++) {
      f32x4 xv[4];
#pragma unroll
      for (int j = 0; j < 4; j++) {
        xv[j] = *(const f32x4*)(xr + j * DIM + lane * 4 + 256 * i);
        u16x4 u;
        u.x = f2b(xv[j].x); u.y = f2b(xv[j].y); u.z = f2b(xv[j].z); u.w = f2b(xv[j].w);
        *(u16x4*)(xbr + j * DIM + lane * 4 + 256 * i) = u;
      }
#pragma unroll
      for (int e = 0; e < NEXP; e++) {
        f32x4 wv = *(const f32x4*)(wr + e * DIM + lane * 4 + 256 * i);
#pragma unroll
        for (int j = 0; j < 4; j++)
          s[j][e] += xv[j].x * wv.x + xv[j].y * wv.y + xv[j].z * wv.z + xv[j].w * wv.w;
      }
    }
#pragma unroll
    for (int j = 0; j < 4; j++)
#pragma unroll
      for (int e = 0; e < NEXP; e++) {
        float v = s[j][e];
#pragma unroll
        for (int off = 32; off > 0; off >>= 1) v += __shfl_xor(v, off);
        s[j][e] = v;
      }
    if (lane == 0) {
#pragma unroll
      for (int j = 0; j < 4; j++) {
        int be = 0;
        float bv = s[j][0];
#pragma unroll
        for (int e = 1; e < NEXP; e++) {
          if (s[j][e] > bv) { bv = s[j][e]; be = e; }
        }
        eid[t0 + j] = be;
      }
    }
  } else {
    const int n4 = NEXP * HID * DIM / 4;
    int stride = NB_CAST * 256;
    for (int i = (bid - NB_ROUTER) * 256 + (int)threadIdx.x; i < n4; i += stride) {
      f32x4 va = ((const f32x4*)wfc)[i];
      f32x4 vb = ((const f32x4*)wpj)[i];
      u16x4 ua, ub;
      ua.x = f2b(va.x); ua.y = f2b(va.y); ua.z = f2b(va.z); ua.w = f2b(va.w);
      ub.x = f2b(vb.x); ub.y = f2b(vb.y); ub.z = f2b(vb.z); ub.w = f2b(vb.w);
      ((u16x4*)oa)[i] = ua;
      ((u16x4*)ob)[i] = ub;
    }
  }
}

__global__ __launch_bounds__(256) void k_hist(const int* __restrict__ eid,
                                              int* __restrict__ bc) {
  __shared__ int h[NEXP];
  if (threadIdx.x < NEXP) h[threadIdx.x] = 0;
  __syncthreads();
  int tok = blockIdx.x * (NTOK / NB_HIST) + threadIdx.x;
  atomicAdd(&h[eid[tok]], 1);
  __syncthreads();
  if (threadIdx.x < NEXP) bc[blockIdx.x * NEXP + threadIdx.x] = h[threadIdx.x];
}

__global__ void k_scan(const int* __restrict__ bc, int* __restrict__ offs,
                       int* __restrict__ base) {
  __shared__ int cnt[NEXP];
  __shared__ int so[NEXP + 1];
  int t = threadIdx.x;
  if (t < NEXP) {
    int run = 0;
    for (int b = 0; b < NB_HIST; b++) {
      base[b * NEXP + t] = run;
      run += bc[b * NEXP + t];
    }
    cnt[t] = run;
  }
  __syncthreads();
  if (t == 0) {
    int a = 0;
    for (int e = 0; e < NEXP; e++) { so[e] = a; a += cnt[e]; }
    so[NEXP] = a;
  }
  __syncthreads();
  if (t < NEXP + 1) offs[t] = so[t];
  for (int i = t; i < NB_HIST * NEXP; i += blockDim.x) base[i] += so[i % NEXP];
}

__global__ __launch_bounds__(256) void k_scatter(const int* __restrict__ eid,
                                                 const int* __restrict__ base,
                                                 int* __restrict__ tlist) {
  __shared__ int cur[NEXP];
  if (threadIdx.x < NEXP) cur[threadIdx.x] = base[blockIdx.x * NEXP + threadIdx.x];
  __syncthreads();
  int tok = blockIdx.x * (NTOK / NB_HIST) + threadIdx.x;
  int e = eid[tok];
  int pos = atomicAdd(&cur[e], 1);
  tlist[pos] = tok;
}

// Grouped GEMM, C[m,n] = sum_k A[m,k]*B[n,k], bf16, K-contiguous.
// BK=32, ring-3 LDS (48 KB -> 3 blocks/CU), depth-2 global_load_lds prefetch,
// one barrier/step, counted vmcnt(4). XOR swizzle chunk ^= row&3 (2-way = free).
// XCD-chunked 1-D grid, (expert, m-block, n-block) with n fastest.
template <int KDIM, int NDIM, int NB, bool IS_FC>
__global__ __launch_bounds__(256) void k_gemm(
    const unsigned short* __restrict__ xb, const unsigned short* __restrict__ hin,
    const unsigned short* __restrict__ wb, const int* __restrict__ offs,
    const int* __restrict__ tlist, unsigned short* __restrict__ hout,
    float* __restrict__ out) {
  int l = ((int)blockIdx.x & 7) * ((int)gridDim.x >> 3) + ((int)blockIdx.x >> 3);
  int e = -1, mb = 0, nb = 0, acc2 = 0;
#pragma unroll
  for (int i = 0; i < NEXP; i++) {
    int mi = offs[i + 1] - offs[i];
    int tb = ((mi + 127) >> 7) * NB;
    if (e < 0 && l < acc2 + tb) {
      int r = l - acc2;
      e = i; mb = r / NB; nb = r % NB;
    }
    acc2 += tb;
  }
  if (e < 0) return;
  int off = offs[e];
  int me = offs[e + 1] - off;
  int m0 = mb * 128;
  int n0 = nb * 128;

  __shared__ unsigned short lds[3][2][128 * 32];  // 48 KB ring-3

  int t = threadIdx.x;
  int lane = t & 63, w = t >> 6;
  int wm = w >> 1, wn = w & 1;  // 2x2 waves, 64x64 each

  int kb = (lane & 3) ^ ((lane >> 2) & 3);

  const unsigned short* asrc[2];
  const unsigned short* bsrc[2];
#pragma unroll
  for (int i = 0; i < 2; i++) {
    int r = i * 64 + w * 16 + (lane >> 2);
    int gm = m0 + r;
    if (gm > me - 1) gm = me - 1;  // clamp pad rows (masked at epilogue)
    if (IS_FC) {
      int tok = tlist[off + gm];
      asrc[i] = xb + (size_t)tok * KDIM + kb * 8;
    } else {
      asrc[i] = hin + (size_t)(off + gm) * KDIM + kb * 8;
    }
    bsrc[i] = wb + ((size_t)e * NDIM + n0 + r) * (size_t)KDIM + kb * 8;
  }

  f32x4 acc[4][4] = {};
  const int NT = KDIM / 32;

  unsigned short* b0a = &lds[0][0][0]; unsigned short* b0b = &lds[0][1][0];
  unsigned short* b1a = &lds[1][0][0]; unsigned short* b1b = &lds[1][1][0];
  unsigned short* b2a = &lds[2][0][0]; unsigned short* b2b = &lds[2][1][0];

#define STAGE(kt_, da_, db_)                                   \
  do {                                                         \
    gload_lds16(asrc[0] + (kt_) * 32, (da_) + (w * 16) * 32);  \
    gload_lds16(asrc[1] + (kt_) * 32, (da_) + (64 + w * 16) * 32); \
    gload_lds16(bsrc[0] + (kt_) * 32, (db_) + (w * 16) * 32);  \
    gload_lds16(bsrc[1] + (kt_) * 32, (db_) + (64 + w * 16) * 32); \
  } while (0)

  STAGE(0, b0a, b0b);
  STAGE(1, b1a, b1b);

  for (int kt = 0; kt < NT; kt++) {
    if (kt < NT - 1) {
      asm volatile("s_waitcnt vmcnt(4)" ::: "memory");
    } else {
      asm volatile("s_waitcnt vmcnt(0)" ::: "memory");
    }
    __builtin_amdgcn_s_barrier();

    if (kt + 2 < NT) STAGE(kt + 2, b2a, b2b);

    short8 af[4], bf[4];
#pragma unroll
    for (int i = 0; i < 4; i++) {
      int ra = wm * 64 + i * 16 + (lane & 15);
      int ca = (lane >> 4) ^ (ra & 3);
      af[i] = *(const short8*)&b0a[ra * 32 + ca * 8];
      int rb = wn * 64 + i * 16 + (lane & 15);
      int cb = (lane >> 4) ^ (rb & 3);
      bf[i] = *(const short8*)&b0b[rb * 32 + cb * 8];
    }
    __builtin_amdgcn_s_setprio(1);
#pragma unroll
    for (int mi = 0; mi < 4; mi++)
#pragma unroll
      for (int ni = 0; ni < 4; ni++)
        acc[mi][ni] =
            __builtin_amdgcn_mfma_f32_16x16x32_bf16(af[mi], bf[ni], acc[mi][ni], 0, 0, 0);
    __builtin_amdgcn_s_setprio(0);

    unsigned short* ta = b0a; b0a = b1a; b1a = b2a; b2a = ta;
    unsigned short* tb = b0b; b0b = b1b; b1b = b2b; b2b = tb;
  }
#undef STAGE

  // C/D layout: col = lane&15, row = (lane>>4)*4 + reg
  int rb = (lane >> 4) * 4, cb = lane & 15;
#pragma unroll
  for (int mi = 0; mi < 4; mi++) {
#pragma unroll
    for (int j = 0; j < 4; j++) {
      int ml = wm * 64 + mi * 16 + rb + j;
      if (m0 + ml < me) {
        if (IS_FC) {
#pragma unroll
          for (int ni = 0; ni < 4; ni++) {
            int col = n0 + wn * 64 + ni * 16 + cb;
            float v = acc[mi][ni][j];
            v = (v >= 0.f) ? v * v : 0.25f * v * v;  // leaky(0.5) then square
            hout[(size_t)(off + m0 + ml) * HID + col] = f2b(v);
          }
        } else {
          int tok = tlist[off + m0 + ml];
#pragma unroll
          for (int ni = 0; ni < 4; ni++) {
            int col = n0 + wn * 64 + ni * 16 + cb;
            out[(size_t)tok * DIM + col] = acc[mi][ni][j];
          }
        }
      }
    }
  }
}

extern "C" void kernel_launch(void* const* d_in, const int* in_sizes, int n_in,
                              void* d_out, int out_size, void* d_ws, size_t ws_size,
                              hipStream_t stream) {
  const float* x = (const float*)d_in[0];
  const float* wr = (const float*)d_in[1];
  const float* wfc = (const float*)d_in[2];
  const float* wpj = (const float*)d_in[3];
  float* out = (float*)d_out;

  uintptr_t p = (uintptr_t)d_ws;
  int* offs = (int*)p;  p += 256;
  int* bc = (int*)p;    p += sizeof(int) * NB_HIST * NEXP;
  int* base = (int*)p;  p += sizeof(int) * NB_HIST * NEXP;
  int* eid = (int*)p;   p += sizeof(int) * NTOK;
  int* tlist = (int*)p; p += sizeof(int) * NTOK;
  unsigned short* wfc_b = (unsigned short*)p; p += (size_t)NEXP * HID * DIM * 2;
  unsigned short* wpj_b = (unsigned short*)p; p += (size_t)NEXP * DIM * HID * 2;
  unsigned short* hbuf = (unsigned short*)p;  p += (size_t)NTOK * HID * 2;
  unsigned short* xb = (unsigned short*)p;    p += (size_t)NTOK * DIM * 2;

  k_router_cast<<<NB_ROUTER + NB_CAST, 256, 0, stream>>>(
      x, wr, eid, xb, wfc, wpj, wfc_b, wpj_b);
  k_hist<<<NB_HIST, 256, 0, stream>>>(eid, bc);
  k_scan<<<1, 256, 0, stream>>>(bc, offs, base);
  k_scatter<<<NB_HIST, 256, 0, stream>>>(eid, base, tlist);
  // fc: max tiles = 135 m-blocks * 4 n-blocks = 540 -> grid 544 (divisible by 8)
  k_gemm<1024, 512, 4, true><<<dim3(544), 256, 0, stream>>>(
      xb, nullptr, wfc_b, offs, tlist, hbuf, nullptr);
  // proj: max tiles = 135 * 8 = 1080 (divisible by 8)
  k_gemm<512, 1024, 8, false><<<dim3(1080), 256, 0, stream>>>(
      nullptr, hbuf, wpj_b, offs, tlist, nullptr, out);
}